// Round 3
// baseline (30150.394 us; speedup 1.0000x reference)
//
#include <hip/hip_runtime.h>
#include <math.h>

// GMM EM, 10 stages, N=65536 D=128 K=16, fp32.
// out = BETA*(z@means_f) + X ; z = memberships from stage 10 E-step.
// v2: estep = LDS-staged X tile (XOR-swizzled) + vector-path W stream,
//     gram = depth-2 software pipeline with vector-path uniform loads.
// All heavy matmuls are fp32 VALU (no fp32 MFMA on CDNA4).

#define NPTS 65536
#define DIM 128
#define KC 16
#define STAGES 10
#define BETA_C 3.0f
#define EPS_C 1e-6f
#define NCH 32
#define NTILES 6
#define CHUNK (NPTS / NCH)

// ---------------------------------------------------------------------------
// prep: per-component Cholesky of (cov + eps I), blocked triangular inverse
// W = L^-1, m = W*mu, kconst = -0.5*logdet. 16 blocks x 256 thr, 149KB LDS.
// ---------------------------------------------------------------------------
__global__ __launch_bounds__(256) void prep_kernel(
    const float* __restrict__ covs, const float* __restrict__ means,
    float* __restrict__ W4, float* __restrict__ mvec, float* __restrict__ kconst)
{
  extern __shared__ float smem[];
  float (*A)[DIM + 1]  = (float (*)[DIM + 1])smem;            // 128*129
  float (*Wv)[DIM + 1] = (float (*)[DIM + 1])(smem + 16512);  // 128*129
  float (*T)[65]       = (float (*)[65])(smem + 33024);       // 64*65
  float* red = smem + 37184;                                  // 128

  const int k = blockIdx.x;
  const int t = threadIdx.x;
  const int tr = t & 127;
  const int th = t >> 7;
  const float* C = covs + (size_t)k * DIM * DIM;

  for (int i = th; i < DIM; i += 2) {
    float v = C[(size_t)i * DIM + tr];
    if (i == tr) v += EPS_C;
    A[i][tr] = v;
    Wv[i][tr] = 0.0f;
  }
  __syncthreads();

  // Cholesky (right-looking, lower triangle in place)
  for (int j = 0; j < DIM; ++j) {
    if (t == 0) A[j][j] = sqrtf(A[j][j]);
    __syncthreads();
    const float Ljj = A[j][j];
    if (th == 0 && tr > j) A[tr][j] /= Ljj;
    __syncthreads();
    if (tr > j) {
      const float aij = A[tr][j];
      for (int l = j + 1 + th; l <= tr; l += 2)
        A[tr][l] -= aij * A[l][j];
    }
    __syncthreads();
  }

  // blocked inverse: W11=L11^-1, W22=L22^-1 (parallel), W21=-W22*(L21*W11)
  if (t < DIM) {
    const int g = t >> 6, c = t & 63, o = g * 64;
    Wv[o + c][o + c] = 1.0f / A[o + c][o + c];
    for (int i = c + 1; i < 64; ++i) {
      float s = 0.0f;
      for (int p = c; p < i; ++p) s += A[o + i][o + p] * Wv[o + p][o + c];
      Wv[o + i][o + c] = -s / A[o + i][o + i];
    }
  }
  __syncthreads();
  for (int idx = t; idx < 4096; idx += 256) {
    const int i = idx >> 6, c = idx & 63;
    float s = 0.0f;
    for (int p = c; p < 64; ++p) s += A[64 + i][p] * Wv[p][c];
    T[i][c] = s;
  }
  __syncthreads();
  for (int idx = t; idx < 4096; idx += 256) {
    const int i = idx >> 6, c = idx & 63;
    float s = 0.0f;
    for (int p = 0; p <= i; ++p) s += Wv[64 + i][64 + p] * T[p][c];
    Wv[64 + i][c] = -s;
  }
  __syncthreads();

  if (t < DIM) {
    const float* mu = means + k * DIM;
    float s = 0.0f;
    for (int e = 0; e <= t; ++e) s += Wv[t][e] * mu[e];
    mvec[k * DIM + t] = s;
    red[t] = logf(A[t][t]);
  }
  __syncthreads();
  if (t == 0) {
    float s = 0.0f;
    for (int i = 0; i < DIM; ++i) s += red[i];
    kconst[k] = -s;  // == -0.5 * logdet
  }
  // W stored interleaved: W4[((k*32+db)*128+e)*4 + j] = W[4*db+j][e]
  for (int idx = t; idx < DIM * DIM; idx += 256) {
    const int d = idx >> 7, e = idx & 127;
    W4[(((size_t)k * 32 + (d >> 2)) * DIM + e) * 4 + (d & 3)] = Wv[d][e];
  }
}

// ---------------------------------------------------------------------------
// estep v2: z[n][k] = softmax_k( -0.5*logdet_k - 0.5*||W_k x_n - m_k||^2 )
// Block = 256 thr (4 waves), 64 rows staged in LDS (4-float-group XOR
// swizzle -> conflict-free ds_read_b128). Wave w handles k in [4w,4w+4) as
// 2 pairs (each x read feeds 32 FMAs -> LDS pipe at ~50%).
// W streamed via vector-path loads (opaque-zero VGPR offset defeats the
// scalar-load path whose ~200cy L2 latency caused the 24% VALUBusy).
// Exact triangular bound: groups g in [0, db] (W upper entries are zero).
// ---------------------------------------------------------------------------
#define PAIR_FMA(xe, a, b)                         \
  ya0 = fmaf(xe, a.x, ya0); ya1 = fmaf(xe, a.y, ya1); \
  ya2 = fmaf(xe, a.z, ya2); ya3 = fmaf(xe, a.w, ya3); \
  yb0 = fmaf(xe, b.x, yb0); yb1 = fmaf(xe, b.y, yb1); \
  yb2 = fmaf(xe, b.z, yb2); yb3 = fmaf(xe, b.w, yb3);

__global__ __launch_bounds__(256, 4) void estep_kernel(
    const float* __restrict__ X, const float* __restrict__ W4,
    const float* __restrict__ mvec, const float* __restrict__ kconst,
    float* __restrict__ Z)
{
  __shared__ float4 xt[64][32];
  __shared__ float lp[64][KC + 1];
  const int tid = threadIdx.x;
  const int lane = tid & 63;
  const int w = tid >> 6;
  const int vzero = __builtin_amdgcn_mbcnt_lo(0u, 0u);  // 0, but in a VGPR

  // stage X tile (64 rows x 128 cols), swizzled at 4-float granularity
  {
    const float4* Xg = (const float4*)(X + (size_t)blockIdx.x * 64 * DIM);
#pragma unroll
    for (int i = 0; i < 8; ++i) {
      const int flat = i * 256 + tid;     // 0..2047 = row*32 + g
      const int r = flat >> 5, g = flat & 31;
      xt[r][g ^ (r & 7)] = Xg[flat];
    }
  }
  __syncthreads();

  const int rs = lane & 7;
#pragma unroll
  for (int kp = 0; kp < 2; ++kp) {
    const int k0 = w * 4 + kp * 2;
    const float4* __restrict__ Wa =
        (const float4*)(W4 + (size_t)k0 * 32 * DIM * 4 + vzero);
    const float4* __restrict__ Wb = Wa + 32 * DIM;
    const float* __restrict__ mk0 = mvec + k0 * DIM;
    const float* __restrict__ mk1 = mk0 + DIM;
    float mahaA = 0.0f, mahaB = 0.0f;
    for (int db = 0; db < 32; ++db) {
      const float4* __restrict__ Wda = Wa + (size_t)db * DIM;
      const float4* __restrict__ Wdb = Wb + (size_t)db * DIM;
      float ya0 = 0, ya1 = 0, ya2 = 0, ya3 = 0;
      float yb0 = 0, yb1 = 0, yb2 = 0, yb3 = 0;
#pragma unroll 2
      for (int g = 0; g <= db; ++g) {     // exact triangle at 4-group level
        const float4 xv = xt[lane][g ^ rs];
        const float4 a0 = Wda[4 * g + 0], b0 = Wdb[4 * g + 0];
        const float4 a1 = Wda[4 * g + 1], b1 = Wdb[4 * g + 1];
        const float4 a2 = Wda[4 * g + 2], b2 = Wdb[4 * g + 2];
        const float4 a3 = Wda[4 * g + 3], b3 = Wdb[4 * g + 3];
        PAIR_FMA(xv.x, a0, b0)
        PAIR_FMA(xv.y, a1, b1)
        PAIR_FMA(xv.z, a2, b2)
        PAIR_FMA(xv.w, a3, b3)
      }
      const int d0 = db * 4;
      {
        const float t0 = ya0 - mk0[d0 + 0], t1 = ya1 - mk0[d0 + 1];
        const float t2 = ya2 - mk0[d0 + 2], t3 = ya3 - mk0[d0 + 3];
        mahaA = fmaf(t0, t0, fmaf(t1, t1, fmaf(t2, t2, fmaf(t3, t3, mahaA))));
      }
      {
        const float t0 = yb0 - mk1[d0 + 0], t1 = yb1 - mk1[d0 + 1];
        const float t2 = yb2 - mk1[d0 + 2], t3 = yb3 - mk1[d0 + 3];
        mahaB = fmaf(t0, t0, fmaf(t1, t1, fmaf(t2, t2, fmaf(t3, t3, mahaB))));
      }
    }
    lp[lane][k0] = kconst[k0] - 0.5f * mahaA;
    lp[lane][k0 + 1] = kconst[k0 + 1] - 0.5f * mahaB;
  }
  __syncthreads();
  if (w == 0) {
    const int row = blockIdx.x * 64 + lane;
    float v[KC];
    float mx = -1e30f;
#pragma unroll
    for (int q = 0; q < KC; ++q) { v[q] = lp[lane][q]; mx = fmaxf(mx, v[q]); }
    float s = 0.0f;
#pragma unroll
    for (int q = 0; q < KC; ++q) { v[q] = expf(v[q] - mx); s += v[q]; }
    const float inv = 1.0f / s;
    float4* zr = (float4*)(Z + (size_t)row * KC);
#pragma unroll
    for (int q = 0; q < KC / 4; ++q)
      zr[q] = make_float4(v[4 * q] * inv, v[4 * q + 1] * inv,
                          v[4 * q + 2] * inv, v[4 * q + 3] * inv);
  }
}

// ---------------------------------------------------------------------------
// gram v2: partial G_k = sum_n z[n][k] * x_n x_n^T over n-chunk, plus s,tw.
// 1 wave/block; lane = local d; 32-col e-tile in regs. Depth-2 software
// pipeline: loads for n+1 issue before FMAs of n (hides per-n latency).
// Uniform operands (z, xs) forced onto the vector path via opaque zero.
// ---------------------------------------------------------------------------
#define GRAM_LOAD(nn, zz, xdv, xs)                                       \
  {                                                                      \
    zz = Zv[(size_t)(nn) * KC + k];                                      \
    xdv = X[(size_t)(nn) * DIM + d];                                     \
    const float4* xp = (const float4*)(Xv + (size_t)(nn) * DIM + e0);    \
    _Pragma("unroll") for (int i = 0; i < 8; ++i) xs[i] = xp[i];         \
  }

#define GRAM_FMA(zz, xdv, xs)                                            \
  {                                                                      \
    const float u = zz * xdv;                                            \
    _Pragma("unroll") for (int i = 0; i < 8; ++i) {                      \
      G[4 * i + 0] = fmaf(u, xs[i].x, G[4 * i + 0]);                     \
      G[4 * i + 1] = fmaf(u, xs[i].y, G[4 * i + 1]);                     \
      G[4 * i + 2] = fmaf(u, xs[i].z, G[4 * i + 2]);                     \
      G[4 * i + 3] = fmaf(u, xs[i].w, G[4 * i + 3]);                     \
    }                                                                    \
    sacc += u;                                                           \
    twacc += zz;                                                         \
  }

__global__ __launch_bounds__(64) void gram_kernel(
    const float* __restrict__ X, const float* __restrict__ Z,
    float* __restrict__ Gp, float* __restrict__ sp, float* __restrict__ twp)
{
  const int k = blockIdx.x;
  const int tile = blockIdx.y;
  const int ch = blockIdx.z;
  const int dh = tile >= 2 ? 1 : 0;
  const int eq = dh ? tile - 2 : tile;
  const int lane = threadIdx.x;
  const int d = dh * 64 + lane;
  const int e0 = eq * 32;
  const int n0 = ch * CHUNK;
  const int vzero = __builtin_amdgcn_mbcnt_lo(0u, 0u);
  const float* __restrict__ Xv = X + vzero;
  const float* __restrict__ Zv = Z + vzero;

  float G[32];
#pragma unroll
  for (int e = 0; e < 32; ++e) G[e] = 0.0f;
  float sacc = 0.0f, twacc = 0.0f;

  float zA, zB, xdA, xdB;
  float4 xsA[8], xsB[8];
  GRAM_LOAD(n0, zA, xdA, xsA)
  for (int n = n0; n < n0 + CHUNK; n += 2) {
    GRAM_LOAD(n + 1, zB, xdB, xsB)
    GRAM_FMA(zA, xdA, xsA)
    const int n2 = (n + 2 < NPTS) ? n + 2 : NPTS - 1;  // clamp last chunk
    GRAM_LOAD(n2, zA, xdA, xsA)
    GRAM_FMA(zB, xdB, xsB)
  }

  float* gout = Gp + (((size_t)ch * KC + k) * NTILES + tile) * 2048;
#pragma unroll
  for (int e = 0; e < 32; ++e) gout[e * 64 + lane] = G[e];  // [e_local][d_local]
  if (eq == 0) {
    sp[((size_t)ch * KC + k) * DIM + d] = sacc;
    if (tile == 0 && lane == 0) twp[ch * KC + k] = twacc;
  }
}

// stage-10 M-step needs only means: first moments without the Gram
__global__ __launch_bounds__(128) void moment_kernel(
    const float* __restrict__ X, const float* __restrict__ Z,
    float* __restrict__ sp, float* __restrict__ twp)
{
  const int k = blockIdx.x;
  const int ch = blockIdx.y;
  const int d = threadIdx.x;
  const int n0 = ch * CHUNK;
  float s = 0.0f, tw = 0.0f;
#pragma unroll 4
  for (int n = n0; n < n0 + CHUNK; ++n) {
    const float zv = Z[(size_t)n * KC + k];
    s = fmaf(zv, X[(size_t)n * DIM + d], s);
    tw += zv;
  }
  sp[((size_t)ch * KC + k) * DIM + d] = s;
  if (d == 0) twp[ch * KC + k] = tw;
}

__global__ __launch_bounds__(256) void reduce_means_kernel(
    const float* __restrict__ sp, const float* __restrict__ twp,
    float* __restrict__ means, float* __restrict__ tw_out)
{
  const int idx = blockIdx.x * 256 + threadIdx.x;  // k*128 + d
  const int k = idx >> 7;
  float tw = 0.0f;
#pragma unroll
  for (int c = 0; c < NCH; ++c) tw += twp[c * KC + k];
  float s = 0.0f;
  for (int c = 0; c < NCH; ++c) s += sp[(size_t)c * KC * DIM + idx];
  means[idx] = s / (tw + EPS_C);
  if ((idx & 127) == 0) tw_out[k] = tw;
}

// cov = G/(tw+eps) - ((tw+2eps)/(tw+eps)) * mu mu^T   (exact expansion of
// sum_n z (x-mu')(x-mu')^T / (tw+eps) with mu' = s/(tw+eps))
__global__ __launch_bounds__(256) void finalize_cov_kernel(
    const float* __restrict__ Gp, const float* __restrict__ means,
    const float* __restrict__ tw_in, float* __restrict__ covs)
{
  const int idx = blockIdx.x * 256 + threadIdx.x;  // k*16384 + d*128 + e
  const int k = idx >> 14;
  const int d = (idx >> 7) & 127;
  const int e = idx & 127;
  const int a = d >= e ? d : e;
  const int b = d >= e ? e : d;
  const int tile = (a >> 6) ? (2 + (b >> 5)) : (b >> 5);
  const int dl = a & 63, el = b & 31;
  float g = 0.0f;
  for (int c = 0; c < NCH; ++c)
    g += Gp[(((size_t)c * KC + k) * NTILES + tile) * 2048 + el * 64 + dl];
  const float tw = tw_in[k];
  const float denom = tw + EPS_C;
  const float md = means[k * DIM + d], me = means[k * DIM + e];
  covs[idx] = g / denom - ((tw + 2.0f * EPS_C) / denom) * md * me;
}

__global__ __launch_bounds__(256) void out_kernel(
    const float* __restrict__ X, const float* __restrict__ Z,
    const float* __restrict__ means, float* __restrict__ out)
{
  const int i4 = blockIdx.x * 256 + threadIdx.x;  // float4 index
  const int n = i4 >> 5;
  const int q = i4 & 31;
  float4 acc = ((const float4*)X)[i4];
  const float* zr = Z + (size_t)n * KC;
#pragma unroll
  for (int k = 0; k < KC; ++k) {
    const float zk = BETA_C * zr[k];
    const float4 mu = ((const float4*)means)[k * 32 + q];
    acc.x = fmaf(zk, mu.x, acc.x);
    acc.y = fmaf(zk, mu.y, acc.y);
    acc.z = fmaf(zk, mu.z, acc.z);
    acc.w = fmaf(zk, mu.w, acc.w);
  }
  ((float4*)out)[i4] = acc;
}

// ---------------------------------------------------------------------------
extern "C" void kernel_launch(void* const* d_in, const int* in_sizes, int n_in,
                              void* d_out, int out_size, void* d_ws, size_t ws_size,
                              hipStream_t stream)
{
  const float* X = (const float*)d_in[0];       // [65536,128]
  const float* means0 = (const float*)d_in[1];  // [16,128]
  const float* covs0 = (const float*)d_in[2];   // [16,128,128]
  float* out = (float*)d_out;                   // [65536,128]
  float* Zout = out + (size_t)NPTS * DIM;       // [65536,16] second output

  // workspace layout (floats); total 6,885,920 floats = 26.3 MiB
  float* ws = (float*)d_ws;
  float* covs_cur  = ws;                  // 262144
  float* W4        = covs_cur + 262144;   // 262144
  float* mvec      = W4 + 262144;         // 2048
  float* kconst    = mvec + 2048;         // 16
  float* tw        = kconst + 16;         // 16
  float* means_cur = tw + 16;             // 2048
  float* sp        = means_cur + 2048;    // 65536
  float* twp       = sp + 65536;          // 512
  float* Gp        = twp + 512;           // 32*16*6*2048 = 6291456

  const int prep_lds = 37312 * 4;  // 149,248 B dynamic LDS
  (void)hipFuncSetAttribute((const void*)prep_kernel,
      hipFuncAttributeMaxDynamicSharedMemorySize, prep_lds);

  for (int s = 0; s < STAGES; ++s) {
    const float* cs = (s == 0) ? covs0 : covs_cur;
    const float* ms = (s == 0) ? means0 : means_cur;
    prep_kernel<<<KC, 256, prep_lds, stream>>>(cs, ms, W4, mvec, kconst);
    estep_kernel<<<NPTS / 64, 256, 0, stream>>>(X, W4, mvec, kconst, Zout);
    if (s < STAGES - 1)
      gram_kernel<<<dim3(KC, NTILES, NCH), 64, 0, stream>>>(X, Zout, Gp, sp, twp);
    else
      moment_kernel<<<dim3(KC, NCH), 128, 0, stream>>>(X, Zout, sp, twp);
    reduce_means_kernel<<<8, 256, 0, stream>>>(sp, twp, means_cur, tw);
    if (s < STAGES - 1)
      finalize_cov_kernel<<<KC * DIM * DIM / 256, 256, 0, stream>>>(
          Gp, means_cur, tw, covs_cur);
  }
  out_kernel<<<(NPTS * DIM / 4) / 256, 256, 0, stream>>>(X, Zout, means_cur, out);
}

// Round 6
// 7687.035 us; speedup vs baseline: 3.9222x; 3.9222x over previous
//
#include <hip/hip_runtime.h>
#include <math.h>

// GMM EM, 10 stages, N=65536 D=128 K=16, fp32 in/out.
// v3.2: = v3.1 (MFMA bf16 2-term split) with XB fragments relocated into the
//   d_out "out" region (32 MiB, free until the final out_kernel) so d_ws use
//   drops to ~19 MB — defends against a possible ws overflow device fault.
// Consistency rule: A and B fragments always packed with the SAME
// (lane-half h = lane>>5, j) -> k map (k = h*8 + j), so the exact HW
// k-ordering cancels. C/D layout: col=lane&31,
// row=(reg&3)+8*(reg>>2)+4*(lane>>5)  [HW-verified per guide].

#define NPTS 65536
#define DIM 128
#define KC 16
#define STAGES 10
#define BETA_C 3.0f
#define EPS_C 1e-6f
#define NCHG 16
#define GCH (NPTS / NCHG)   // 4096 n per gram chunk
#define GSUB (GCH / 64)     // 64 subtiles of 64 n

typedef __attribute__((ext_vector_type(8))) short bfrag_t;   // 8 bf16
typedef __attribute__((ext_vector_type(16))) float f32x16;

__device__ __forceinline__ unsigned short bf_hi(float f) {
  unsigned u = __float_as_uint(f);
  return (unsigned short)((u + 0x7fffu + ((u >> 16) & 1u)) >> 16);  // RNE
}
__device__ __forceinline__ float bf_f(unsigned short h) {
  return __uint_as_float((unsigned)h << 16);
}
__device__ __forceinline__ bfrag_t bc(int4 v) {
  return __builtin_bit_cast(bfrag_t, v);
}

// split 8 fp32 into hi/lo bf16 int4-packs (k = h*8+j order preserved)
#define SPLIT_PACK(V0, V1, V2, V3, V4, V5, V6, V7, HI, LO)                    \
  {                                                                           \
    const unsigned short h0 = bf_hi(V0), h1 = bf_hi(V1), h2 = bf_hi(V2),      \
                         h3 = bf_hi(V3), h4 = bf_hi(V4), h5 = bf_hi(V5),      \
                         h6 = bf_hi(V6), h7 = bf_hi(V7);                      \
    (HI).x = (int)((unsigned)h0 | ((unsigned)h1 << 16));                      \
    (HI).y = (int)((unsigned)h2 | ((unsigned)h3 << 16));                      \
    (HI).z = (int)((unsigned)h4 | ((unsigned)h5 << 16));                      \
    (HI).w = (int)((unsigned)h6 | ((unsigned)h7 << 16));                      \
    const unsigned short l0 = bf_hi((V0) - bf_f(h0)),                         \
                         l1 = bf_hi((V1) - bf_f(h1)),                         \
                         l2 = bf_hi((V2) - bf_f(h2)),                         \
                         l3 = bf_hi((V3) - bf_f(h3)),                         \
                         l4 = bf_hi((V4) - bf_f(h4)),                         \
                         l5 = bf_hi((V5) - bf_f(h5)),                         \
                         l6 = bf_hi((V6) - bf_f(h6)),                         \
                         l7 = bf_hi((V7) - bf_f(h7));                         \
    (LO).x = (int)((unsigned)l0 | ((unsigned)l1 << 16));                      \
    (LO).y = (int)((unsigned)l2 | ((unsigned)l3 << 16));                      \
    (LO).z = (int)((unsigned)l4 | ((unsigned)l5 << 16));                      \
    (LO).w = (int)((unsigned)l6 | ((unsigned)l7 << 16));                      \
  }

// ---------------------------------------------------------------------------
// xsplit (once per launch): X bf16 hi/lo in gram-B fragment layout
// XB[nb][e][h] int4 ; element j is n = nb*16 + h*8 + j, column e.
// ---------------------------------------------------------------------------
__global__ __launch_bounds__(256) void xsplit_kernel(
    const float* __restrict__ X, int4* __restrict__ XBh, int4* __restrict__ XBl)
{
  const int nb = blockIdx.x;
  const int t = threadIdx.x;
  const int e = t >> 1, h = t & 1;
  float v[8];
#pragma unroll
  for (int j = 0; j < 8; ++j)
    v[j] = X[(size_t)(nb * 16 + h * 8 + j) * DIM + e];
  int4 hi, lo;
  SPLIT_PACK(v[0], v[1], v[2], v[3], v[4], v[5], v[6], v[7], hi, lo)
  const size_t idx = ((size_t)nb * DIM + e) * 2 + h;
  XBh[idx] = hi;
  XBl[idx] = lo;
}

// ---------------------------------------------------------------------------
// prep: Cholesky of (cov+eps I), blocked inverse W=L^-1, m=W*mu,
// kconst=-0.5*logdet; emits W as estep-B fragments (hi/lo bf16):
// WB[k][es][d][h] int4, element j is e = es*16 + h*8 + j.  149KB dyn LDS.
// ---------------------------------------------------------------------------
__global__ __launch_bounds__(256) void prep_kernel(
    const float* __restrict__ covs, const float* __restrict__ means,
    int4* __restrict__ WBh, int4* __restrict__ WBl,
    float* __restrict__ mvec, float* __restrict__ kconst)
{
  extern __shared__ float smem[];
  float (*A)[DIM + 1]  = (float (*)[DIM + 1])smem;            // 128*129
  float (*Wv)[DIM + 1] = (float (*)[DIM + 1])(smem + 16512);  // 128*129
  float (*T)[65]       = (float (*)[65])(smem + 33024);       // 64*65
  float* red = smem + 37184;                                  // 128

  const int k = blockIdx.x;
  const int t = threadIdx.x;
  const int tr = t & 127;
  const int th = t >> 7;
  const float* C = covs + (size_t)k * DIM * DIM;

  for (int i = th; i < DIM; i += 2) {
    float v = C[(size_t)i * DIM + tr];
    if (i == tr) v += EPS_C;
    A[i][tr] = v;
    Wv[i][tr] = 0.0f;
  }
  __syncthreads();

  for (int j = 0; j < DIM; ++j) {
    if (t == 0) A[j][j] = sqrtf(A[j][j]);
    __syncthreads();
    const float Ljj = A[j][j];
    if (th == 0 && tr > j) A[tr][j] /= Ljj;
    __syncthreads();
    if (tr > j) {
      const float aij = A[tr][j];
      for (int l = j + 1 + th; l <= tr; l += 2)
        A[tr][l] -= aij * A[l][j];
    }
    __syncthreads();
  }

  if (t < DIM) {
    const int g = t >> 6, c = t & 63, o = g * 64;
    Wv[o + c][o + c] = 1.0f / A[o + c][o + c];
    for (int i = c + 1; i < 64; ++i) {
      float s = 0.0f;
      for (int p = c; p < i; ++p) s += A[o + i][o + p] * Wv[o + p][o + c];
      Wv[o + i][o + c] = -s / A[o + i][o + i];
    }
  }
  __syncthreads();
  for (int idx = t; idx < 4096; idx += 256) {
    const int i = idx >> 6, c = idx & 63;
    float s = 0.0f;
    for (int p = c; p < 64; ++p) s += A[64 + i][p] * Wv[p][c];
    T[i][c] = s;
  }
  __syncthreads();
  for (int idx = t; idx < 4096; idx += 256) {
    const int i = idx >> 6, c = idx & 63;
    float s = 0.0f;
    for (int p = 0; p <= i; ++p) s += Wv[64 + i][64 + p] * T[p][c];
    Wv[64 + i][c] = -s;
  }
  __syncthreads();

  if (t < DIM) {
    const float* mu = means + k * DIM;
    float s = 0.0f;
    for (int e = 0; e <= t; ++e) s += Wv[t][e] * mu[e];
    mvec[k * DIM + t] = s;
    red[t] = logf(A[t][t]);
  }
  __syncthreads();
  if (t == 0) {
    float s = 0.0f;
    for (int i = 0; i < DIM; ++i) s += red[i];
    kconst[k] = -s;  // == -0.5*logdet
  }
  // emit W fragments: d = t&127 (row of W), h = t>>7
  {
    const int d = t & 127, h = t >> 7;
#pragma unroll
    for (int es = 0; es < 8; ++es) {
      float v[8];
#pragma unroll
      for (int j = 0; j < 8; ++j) v[j] = Wv[d][es * 16 + h * 8 + j];
      int4 hi, lo;
      SPLIT_PACK(v[0], v[1], v[2], v[3], v[4], v[5], v[6], v[7], hi, lo)
      const size_t idx = ((size_t)(k * 8 + es) * DIM + d) * 2 + h;
      WBh[idx] = hi;
      WBl[idx] = lo;
    }
  }
}

// ---------------------------------------------------------------------------
// estep: Y = X*W_k^T via MFMA (3-pass bf16 split), maha = ||Y - m||^2,
// softmax over k.  Block = 256 thr (4 waves x 32 n-rows = 128 rows).
// A (X frags) split per-block into LDS once, preloaded to VGPRs, reused 16k.
// B (W frags) streamed from global WB (L2-hot, 1MB total).
// Triangle skip: d-tile DT only needs e-steps es <= 2*DT+1.
// ---------------------------------------------------------------------------
#define EST_DT(DT)                                                            \
  {                                                                           \
    f32x16 accv;                                                              \
    _Pragma("unroll") for (int r = 0; r < 16; ++r) accv[r] = 0.0f;            \
    _Pragma("unroll") for (int es = 0; es < 2 * (DT) + 2; ++es) {             \
      const size_t wb = ((size_t)(k * 8 + es) * DIM + (DT) * 32 + c31) * 2 + hh; \
      const int4 bh = WBh[wb];                                                \
      const int4 bl = WBl[wb];                                                \
      accv = __builtin_amdgcn_mfma_f32_32x32x16_bf16(bc(axl[es]), bc(bh), accv, 0, 0, 0); \
      accv = __builtin_amdgcn_mfma_f32_32x32x16_bf16(bc(axh[es]), bc(bl), accv, 0, 0, 0); \
      accv = __builtin_amdgcn_mfma_f32_32x32x16_bf16(bc(axh[es]), bc(bh), accv, 0, 0, 0); \
    }                                                                         \
    const float mval = mvec[k * DIM + (DT) * 32 + c31];                       \
    _Pragma("unroll") for (int r = 0; r < 16; ++r) {                          \
      const float v = accv[r] - mval;                                         \
      part[r] = fmaf(v, v, part[r]);                                          \
    }                                                                         \
  }

__global__ __launch_bounds__(256, 2) void estep_kernel(
    const float* __restrict__ X, const int4* __restrict__ WBh,
    const int4* __restrict__ WBl, const float* __restrict__ mvec,
    const float* __restrict__ kconst, float* __restrict__ Z)
{
  __shared__ int4 XAh[8][128][2];  // 32KB  (A frags hi) — lp aliases this
  __shared__ int4 XAl[8][128][2];  // 32KB  (A frags lo)
  float (*lp)[KC + 1] = (float (*)[KC + 1]) & XAh[0][0][0];  // 128x17 = 8.5KB

  const int tid = threadIdx.x;
  const int c31 = tid & 31;
  const int hh = (tid & 63) >> 5;
  const int w = tid >> 6;
  const size_t n0 = (size_t)blockIdx.x * 128;

  // stage X fragments: thread (n = tid&127, h2 = tid>>7), 8 es each
  {
    const int n = tid & 127, h2 = tid >> 7;
    const int hsw = h2 ^ ((n >> 2) & 1);  // LDS h-slot swizzle
    const float4* xr = (const float4*)(X + (n0 + n) * DIM);
#pragma unroll
    for (int es = 0; es < 8; ++es) {
      const float4 a = xr[es * 4 + h2 * 2];
      const float4 b = xr[es * 4 + h2 * 2 + 1];
      int4 hi, lo;
      SPLIT_PACK(a.x, a.y, a.z, a.w, b.x, b.y, b.z, b.w, hi, lo)
      XAh[es][n][hsw] = hi;
      XAl[es][n][hsw] = lo;
    }
  }
  __syncthreads();

  // preload this wave's A fragments (rows w*32 + c31), reused for all k
  int4 axh[8], axl[8];
  {
    const int nl = w * 32 + c31;
    const int hsw = hh ^ ((nl >> 2) & 1);
#pragma unroll
    for (int es = 0; es < 8; ++es) {
      axh[es] = XAh[es][nl][hsw];
      axl[es] = XAl[es][nl][hsw];
    }
  }
  __syncthreads();  // XAh now dead -> lp may be written

  for (int k = 0; k < KC; ++k) {
    float part[16];
#pragma unroll
    for (int r = 0; r < 16; ++r) part[r] = 0.0f;
    EST_DT(0)
    EST_DT(1)
    EST_DT(2)
    EST_DT(3)
    // reduce across the 32 cols (halves stay separate: masks < 32)
#pragma unroll
    for (int off = 1; off < 32; off <<= 1) {
#pragma unroll
      for (int r = 0; r < 16; ++r) part[r] += __shfl_xor(part[r], off, 64);
    }
    float sel = 0.0f;
#pragma unroll
    for (int r = 0; r < 16; ++r) sel = (c31 == r) ? part[r] : sel;
    if (c31 < 16) {
      const int row = (c31 & 3) + 8 * (c31 >> 2) + 4 * hh;
      lp[w * 32 + row][k] = kconst[k] - 0.5f * sel;
    }
  }
  __syncthreads();

  if (tid < 128) {
    float v[KC];
    float mx = -1e30f;
#pragma unroll
    for (int q = 0; q < KC; ++q) { v[q] = lp[tid][q]; mx = fmaxf(mx, v[q]); }
    float s = 0.0f;
#pragma unroll
    for (int q = 0; q < KC; ++q) { v[q] = expf(v[q] - mx); s += v[q]; }
    const float inv = 1.0f / s;
    float4* zr = (float4*)(Z + (n0 + tid) * KC);
#pragma unroll
    for (int q = 0; q < KC / 4; ++q)
      zr[q] = make_float4(v[4 * q] * inv, v[4 * q + 1] * inv,
                          v[4 * q + 2] * inv, v[4 * q + 3] * inv);
  }
}

// ---------------------------------------------------------------------------
// gram: G_k[d][e] = sum_n (z*x_d) x_e via MFMA, fused s_k[d] and tw_k.
// Block (k, ch, dh): 64-d half x 128 e, chunk of 4096 n, 4 waves.
// A = z*x product-split in LDS (double-buffered, h-slot XOR swizzle),
// B = XB global frags.  Wave w: d-tile w&1, e-tiles {2*(w>>1), +1}.
// ---------------------------------------------------------------------------
#define GPREP(SUB, BUF)                                                       \
  {                                                                           \
    _Pragma("unroll") for (int q = 0; q < 2; ++q) {                           \
      const int ns = 2 * ns2 + q;                                             \
      const int nb = n0 + (SUB) * 64 + ns * 16 + hq * 8;                      \
      float p[8];                                                             \
      _Pragma("unroll") for (int j = 0; j < 8; ++j) {                         \
        const float xv = X[(size_t)(nb + j) * DIM + dglob];                   \
        const float zv = Z[(size_t)(nb + j) * KC + k];                        \
        p[j] = zv * xv;                                                       \
        sacc += p[j];                                                         \
      }                                                                       \
      int4 hi, lo;                                                            \
      SPLIT_PACK(p[0], p[1], p[2], p[3], p[4], p[5], p[6], p[7], hi, lo)      \
      PAh[BUF][ns][dl][hsw] = hi;                                             \
      PAl[BUF][ns][dl][hsw] = lo;                                             \
    }                                                                         \
  }

__global__ __launch_bounds__(256, 2) void gram_kernel(
    const float* __restrict__ X, const float* __restrict__ Z,
    const int4* __restrict__ XBh, const int4* __restrict__ XBl,
    float* __restrict__ Gp, float* __restrict__ sp, float* __restrict__ twp)
{
  __shared__ int4 PAh[2][4][64][2];  // 16KB
  __shared__ int4 PAl[2][4][64][2];  // 16KB
  __shared__ float sred[64][4];

  const int k = blockIdx.x;
  const int ch = blockIdx.y;
  const int dh = blockIdx.z;
  const int tid = threadIdx.x;
  const int n0 = ch * GCH;

  // prep-role indices
  const int dl = tid & 63;
  const int hq = (tid >> 6) & 1;
  const int ns2 = tid >> 7;
  const int hsw = hq ^ ((dl >> 2) & 1);
  const int dglob = dh * 64 + dl;

  // mfma-role indices
  const int c31 = tid & 31;
  const int hh = (tid & 63) >> 5;
  const int w = tid >> 6;
  const int dt = w & 1;
  const int et0 = (w >> 1) * 2;
  const int drd = dt * 32 + c31;
  const int hrd = hh ^ ((drd >> 2) & 1);

  f32x16 acc0, acc1;
#pragma unroll
  for (int r = 0; r < 16; ++r) { acc0[r] = 0.0f; acc1[r] = 0.0f; }
  float sacc = 0.0f;

  GPREP(0, 0)
  __syncthreads();
  int buf = 0;
  for (int sub = 0; sub < GSUB; ++sub) {
    if (sub + 1 < GSUB) GPREP(sub + 1, buf ^ 1)
#pragma unroll
    for (int ns = 0; ns < 4; ++ns) {
      const int4 ah = PAh[buf][ns][drd][hrd];
      const int4 al = PAl[buf][ns][drd][hrd];
      const size_t nb16 = (size_t)(n0 + sub * 64 + ns * 16) >> 4;
      const size_t b0 = (nb16 * DIM + (et0 + 0) * 32 + c31) * 2 + hh;
      const size_t b1 = (nb16 * DIM + (et0 + 1) * 32 + c31) * 2 + hh;
      {
        const int4 bh = XBh[b0], bl = XBl[b0];
        acc0 = __builtin_amdgcn_mfma_f32_32x32x16_bf16(bc(al), bc(bh), acc0, 0, 0, 0);
        acc0 = __builtin_amdgcn_mfma_f32_32x32x16_bf16(bc(ah), bc(bl), acc0, 0, 0, 0);
        acc0 = __builtin_amdgcn_mfma_f32_32x32x16_bf16(bc(ah), bc(bh), acc0, 0, 0, 0);
      }
      {
        const int4 bh = XBh[b1], bl = XBl[b1];
        acc1 = __builtin_amdgcn_mfma_f32_32x32x16_bf16(bc(al), bc(bh), acc1, 0, 0, 0);
        acc1 = __builtin_amdgcn_mfma_f32_32x32x16_bf16(bc(ah), bc(bl), acc1, 0, 0, 0);
        acc1 = __builtin_amdgcn_mfma_f32_32x32x16_bf16(bc(ah), bc(bh), acc1, 0, 0, 0);
      }
    }
    __syncthreads();
    buf ^= 1;
  }

  // store G tiles: d = dh*64 + dt*32 + row(reg), e = (et0+ei)*32 + c31
  {
    float* gbase = Gp + (size_t)(ch * KC + k) * (DIM * DIM);
#pragma unroll
    for (int r = 0; r < 16; ++r) {
      const int row = (r & 3) + 8 * (r >> 2) + 4 * hh;
      const int d = dh * 64 + dt * 32 + row;
      gbase[(size_t)d * DIM + (et0 + 0) * 32 + c31] = acc0[r];
      gbase[(size_t)d * DIM + (et0 + 1) * 32 + c31] = acc1[r];
    }
  }

  // fused first moment + total weight
  sred[dl][tid >> 6] = sacc;
  __syncthreads();
  if (tid < 64) {
    const float s = sred[tid][0] + sred[tid][1] + sred[tid][2] + sred[tid][3];
    sp[(size_t)(ch * KC + k) * DIM + dh * 64 + tid] = s;
  }
  if (dh == 0 && tid < 64) {
    float tz = 0.0f;
    for (int i = 0; i < GCH / 64; ++i)      // full chunk (v3.1 fix)
      tz += Z[(size_t)(n0 + tid + 64 * i) * KC + k];
#pragma unroll
    for (int off = 1; off < 64; off <<= 1) tz += __shfl_xor(tz, off, 64);
    if (tid == 0) twp[ch * KC + k] = tz;
  }
}

__global__ __launch_bounds__(256) void reduce_means_kernel(
    const float* __restrict__ sp, const float* __restrict__ twp,
    float* __restrict__ means, float* __restrict__ tw_out)
{
  const int idx = blockIdx.x * 256 + threadIdx.x;  // k*128 + d
  const int k = idx >> 7;
  float tw = 0.0f;
#pragma unroll
  for (int c = 0; c < NCHG; ++c) tw += twp[c * KC + k];
  float s = 0.0f;
  for (int c = 0; c < NCHG; ++c) s += sp[(size_t)c * KC * DIM + idx];
  means[idx] = s / (tw + EPS_C);
  if ((idx & 127) == 0) tw_out[k] = tw;
}

// cov = G/(tw+eps) - ((tw+2eps)/(tw+eps)) * mu mu^T  (exact expansion)
__global__ __launch_bounds__(256) void finalize_cov_kernel(
    const float* __restrict__ Gp, const float* __restrict__ means,
    const float* __restrict__ tw_in, float* __restrict__ covs)
{
  const int idx = blockIdx.x * 256 + threadIdx.x;  // k*16384 + d*128 + e
  const int k = idx >> 14;
  const int d = (idx >> 7) & 127;
  const int e = idx & 127;
  float g = 0.0f;
  for (int c = 0; c < NCHG; ++c)
    g += Gp[(size_t)(c * KC + k) * (DIM * DIM) + d * DIM + e];
  const float tw = tw_in[k];
  const float denom = tw + EPS_C;
  const float md = means[k * DIM + d], me = means[k * DIM + e];
  covs[idx] = g / denom - ((tw + 2.0f * EPS_C) / denom) * md * me;
}

__global__ __launch_bounds__(256) void out_kernel(
    const float* __restrict__ X, const float* __restrict__ Z,
    const float* __restrict__ means, float* __restrict__ out)
{
  const int i4 = blockIdx.x * 256 + threadIdx.x;  // float4 index
  const int n = i4 >> 5;
  const int q = i4 & 31;
  float4 acc = ((const float4*)X)[i4];
  const float* zr = Z + (size_t)n * KC;
#pragma unroll
  for (int k = 0; k < KC; ++k) {
    const float zk = BETA_C * zr[k];
    const float4 mu = ((const float4*)means)[k * 32 + q];
    acc.x = fmaf(zk, mu.x, acc.x);
    acc.y = fmaf(zk, mu.y, acc.y);
    acc.z = fmaf(zk, mu.z, acc.z);
    acc.w = fmaf(zk, mu.w, acc.w);
  }
  ((float4*)out)[i4] = acc;
}

// ---------------------------------------------------------------------------
extern "C" void kernel_launch(void* const* d_in, const int* in_sizes, int n_in,
                              void* d_out, int out_size, void* d_ws, size_t ws_size,
                              hipStream_t stream)
{
  const float* X = (const float*)d_in[0];       // [65536,128]
  const float* means0 = (const float*)d_in[1];  // [16,128]
  const float* covs0 = (const float*)d_in[2];   // [16,128,128]
  float* out = (float*)d_out;                   // [65536,128]
  float* Zout = out + (size_t)NPTS * DIM;       // [65536,16] second output

  // XB fragments live in the d_out "out" region (32 MiB, exactly fits):
  // only out_kernel (the last launch) writes `out`, and it never reads XB.
  int4* XBh = (int4*)out;                                 // 16 MiB
  int4* XBl = XBh + (size_t)(NPTS / 16) * DIM * 2;        // 16 MiB

  // workspace (bytes): ~19 MB total (known-good budget is >= 26.3 MB)
  char* p = (char*)d_ws;
  float* covs_cur  = (float*)p;  p += (size_t)262144 * 4;          // 1MB
  float* mvec      = (float*)p;  p += 2048 * 4;
  float* kconst    = (float*)p;  p += 64;
  float* tw        = (float*)p;  p += 64;
  float* means_cur = (float*)p;  p += 2048 * 4;
  float* sp        = (float*)p;  p += (size_t)NCHG * KC * DIM * 4; // 128KB
  float* twp       = (float*)p;  p += NCHG * KC * 4;
  int4* WBh        = (int4*)p;   p += (size_t)KC * 8 * DIM * 2 * 16;   // 512KB
  int4* WBl        = (int4*)p;   p += (size_t)KC * 8 * DIM * 2 * 16;   // 512KB
  float* Gp        = (float*)p;  p += (size_t)NCHG * KC * DIM * DIM * 4;  // 16.8MB

  const int prep_lds = 37312 * 4;  // 149,248 B dynamic LDS
  (void)hipFuncSetAttribute((const void*)prep_kernel,
      hipFuncAttributeMaxDynamicSharedMemorySize, prep_lds);

  xsplit_kernel<<<NPTS / 16, 256, 0, stream>>>(X, XBh, XBl);

  for (int s = 0; s < STAGES; ++s) {
    const float* cs = (s == 0) ? covs0 : covs_cur;
    const float* ms = (s == 0) ? means0 : means_cur;
    prep_kernel<<<KC, 256, prep_lds, stream>>>(cs, ms, WBh, WBl, mvec, kconst);
    estep_kernel<<<NPTS / 128, 256, 0, stream>>>(X, WBh, WBl, mvec, kconst, Zout);
    gram_kernel<<<dim3(KC, NCHG, 2), 256, 0, stream>>>(X, Zout, XBh, XBl, Gp, sp, twp);
    reduce_means_kernel<<<8, 256, 0, stream>>>(sp, twp, means_cur, tw);
    if (s < STAGES - 1)
      finalize_cov_kernel<<<KC * DIM * DIM / 256, 256, 0, stream>>>(
          Gp, means_cur, tw, covs_cur);
  }
  out_kernel<<<(NPTS * DIM / 4) / 256, 256, 0, stream>>>(X, Zout, means_cur, out);
}

// Round 7
// 5884.621 us; speedup vs baseline: 5.1236x; 1.3063x over previous
//
#include <hip/hip_runtime.h>
#include <math.h>

// GMM EM, 10 stages, N=65536 D=128 K=16, fp32 in/out.
// v4: - prep: blocked Cholesky NB=16 (wave-sync diagonal, ~24 barriers vs 512)
//     - gram: LDS-free; A-fragments built in registers from XB + transposed Zt
//     - estep: unchanged MFMA path, + writes Zt[k][n] (coalesced) for gram
// Consistency rule: A and B fragments always packed with the SAME
// (lane-half h = lane>>5, j) -> k map (k = h*8 + j). C/D layout: col=lane&31,
// row=(reg&3)+8*(reg>>2)+4*(lane>>5)  [HW-verified; validated by v3.2 pass].

#define NPTS 65536
#define DIM 128
#define KC 16
#define STAGES 10
#define BETA_C 3.0f
#define EPS_C 1e-6f
#define NCHG 16
#define GCH (NPTS / NCHG)   // 4096 n per gram chunk

typedef __attribute__((ext_vector_type(8))) short bfrag_t;   // 8 bf16
typedef __attribute__((ext_vector_type(16))) float f32x16;

__device__ __forceinline__ unsigned short bf_hi(float f) {
  unsigned u = __float_as_uint(f);
  return (unsigned short)((u + 0x7fffu + ((u >> 16) & 1u)) >> 16);  // RNE
}
__device__ __forceinline__ float bf_f(unsigned short h) {
  return __uint_as_float((unsigned)h << 16);
}
__device__ __forceinline__ bfrag_t bc(int4 v) {
  return __builtin_bit_cast(bfrag_t, v);
}

// split 8 fp32 into hi/lo bf16 int4-packs (k = h*8+j order preserved)
#define SPLIT_PACK(V0, V1, V2, V3, V4, V5, V6, V7, HI, LO)                    \
  {                                                                           \
    const unsigned short h0 = bf_hi(V0), h1 = bf_hi(V1), h2 = bf_hi(V2),      \
                         h3 = bf_hi(V3), h4 = bf_hi(V4), h5 = bf_hi(V5),      \
                         h6 = bf_hi(V6), h7 = bf_hi(V7);                      \
    (HI).x = (int)((unsigned)h0 | ((unsigned)h1 << 16));                      \
    (HI).y = (int)((unsigned)h2 | ((unsigned)h3 << 16));                      \
    (HI).z = (int)((unsigned)h4 | ((unsigned)h5 << 16));                      \
    (HI).w = (int)((unsigned)h6 | ((unsigned)h7 << 16));                      \
    const unsigned short l0 = bf_hi((V0) - bf_f(h0)),                         \
                         l1 = bf_hi((V1) - bf_f(h1)),                         \
                         l2 = bf_hi((V2) - bf_f(h2)),                         \
                         l3 = bf_hi((V3) - bf_f(h3)),                         \
                         l4 = bf_hi((V4) - bf_f(h4)),                         \
                         l5 = bf_hi((V5) - bf_f(h5)),                         \
                         l6 = bf_hi((V6) - bf_f(h6)),                         \
                         l7 = bf_hi((V7) - bf_f(h7));                         \
    (LO).x = (int)((unsigned)l0 | ((unsigned)l1 << 16));                      \
    (LO).y = (int)((unsigned)l2 | ((unsigned)l3 << 16));                      \
    (LO).z = (int)((unsigned)l4 | ((unsigned)l5 << 16));                      \
    (LO).w = (int)((unsigned)l6 | ((unsigned)l7 << 16));                      \
  }

// ---------------------------------------------------------------------------
// xsplit (once per launch): X bf16 hi/lo in B-fragment layout
// XB[nb][e][h] int4 ; element j is n = nb*16 + h*8 + j, column e.
// ---------------------------------------------------------------------------
__global__ __launch_bounds__(256) void xsplit_kernel(
    const float* __restrict__ X, int4* __restrict__ XBh, int4* __restrict__ XBl)
{
  const int nb = blockIdx.x;
  const int t = threadIdx.x;
  const int e = t >> 1, h = t & 1;
  float v[8];
#pragma unroll
  for (int j = 0; j < 8; ++j)
    v[j] = X[(size_t)(nb * 16 + h * 8 + j) * DIM + e];
  int4 hi, lo;
  SPLIT_PACK(v[0], v[1], v[2], v[3], v[4], v[5], v[6], v[7], hi, lo)
  const size_t idx = ((size_t)nb * DIM + e) * 2 + h;
  XBh[idx] = hi;
  XBl[idx] = lo;
}

// ---------------------------------------------------------------------------
// prep v2: BLOCKED Cholesky (NB=16) of (cov+eps I), blocked triangular
// inverse W=L^-1, m=W*mu, kconst=-0.5*logdet; emits W as estep-B fragments.
// Diagonal block: wave-synchronous in wave 0 (no block barriers inside).
// ~24 block barriers total (was 512).  149KB dyn LDS.
// ---------------------------------------------------------------------------
__global__ __launch_bounds__(256) void prep_kernel(
    const float* __restrict__ covs, const float* __restrict__ means,
    int4* __restrict__ WBh, int4* __restrict__ WBl,
    float* __restrict__ mvec, float* __restrict__ kconst)
{
  extern __shared__ float smem[];
  float (*A)[DIM + 1]  = (float (*)[DIM + 1])smem;            // 128*129
  float (*Wv)[DIM + 1] = (float (*)[DIM + 1])(smem + 16512);  // 128*129
  float (*T)[65]       = (float (*)[65])(smem + 33024);       // 64*65
  float* red = smem + 37184;                                  // 128

  const int k = blockIdx.x;
  const int t = threadIdx.x;
  const int lane = t & 63;
  const int wv = t >> 6;
  const float* C = covs + (size_t)k * DIM * DIM;

  {
    const int tr = t & 127, th = t >> 7;
    for (int i = th; i < DIM; i += 2) {
      float v = C[(size_t)i * DIM + tr];
      if (i == tr) v += EPS_C;
      A[i][tr] = v;
      Wv[i][tr] = 0.0f;
    }
  }
  __syncthreads();

  // ---- blocked Cholesky, NB=16 ----
  for (int b = 0; b < 8; ++b) {
    const int o = b * 16;
    // 1) 16x16 diagonal factor, wave 0, wave-synchronous
    if (wv == 0) {
      const int l = lane;
      for (int j = 0; j < 16; ++j) {
        const float djj = sqrtf(A[o + j][o + j]);
        if (l == j) A[o + j][o + j] = djj;
        if (l > j && l < 16) {
          A[o + l][o + j] /= djj;
          const float f = A[o + l][o + j];
          for (int c = j + 1; c <= l; ++c)
            A[o + l][o + c] -= f * A[o + c][o + j];
        }
      }
    }
    __syncthreads();
    const int nr = DIM - o - 16;  // rows below the diagonal block
    if (nr > 0) {
      // 2) panel solve: row i = o+16+t, L[i][o:o+16] = A[i][..] inv(D)^T
      if (t < nr) {
        const int i = o + 16 + t;
        float li[16];
#pragma unroll
        for (int c = 0; c < 16; ++c) {
          float s = A[i][o + c];
#pragma unroll
          for (int p = 0; p < c; ++p) s -= li[p] * A[o + c][o + p];
          li[c] = s / A[o + c][o + c];
          A[i][o + c] = li[c];
        }
      }
      __syncthreads();
      // 3) trailing rank-16 update (lower triangle), 2 threads/row
      {
        const int ir = t >> 1, half = t & 1;
        if (ir < nr) {
          const int i = o + 16 + ir;
          float li[16];
#pragma unroll
          for (int p = 0; p < 16; ++p) li[p] = A[i][o + p];
          for (int j = o + 16 + half; j <= i; j += 2) {
            float s = A[i][j];
#pragma unroll
            for (int p = 0; p < 16; ++p) s -= li[p] * A[j][o + p];
            A[i][j] = s;
          }
        }
      }
      __syncthreads();
    }
  }

  // ---- blocked inverse: W11=L11^-1, W22=L22^-1, W21=-W22*(L21*W11) ----
  if (t < DIM) {
    const int g = t >> 6, c = t & 63, o = g * 64;
    Wv[o + c][o + c] = 1.0f / A[o + c][o + c];
    for (int i = c + 1; i < 64; ++i) {
      float s = 0.0f;
      for (int p = c; p < i; ++p) s += A[o + i][o + p] * Wv[o + p][o + c];
      Wv[o + i][o + c] = -s / A[o + i][o + i];
    }
  }
  __syncthreads();
  for (int idx = t; idx < 4096; idx += 256) {
    const int i = idx >> 6, c = idx & 63;
    float s = 0.0f;
    for (int p = c; p < 64; ++p) s += A[64 + i][p] * Wv[p][c];
    T[i][c] = s;
  }
  __syncthreads();
  for (int idx = t; idx < 4096; idx += 256) {
    const int i = idx >> 6, c = idx & 63;
    float s = 0.0f;
    for (int p = 0; p <= i; ++p) s += Wv[64 + i][64 + p] * T[p][c];
    Wv[64 + i][c] = -s;
  }
  __syncthreads();

  if (t < DIM) {
    const float* mu = means + k * DIM;
    float s = 0.0f;
    for (int e = 0; e <= t; ++e) s += Wv[t][e] * mu[e];
    mvec[k * DIM + t] = s;
    red[t] = logf(A[t][t]);
  }
  __syncthreads();
  if (t == 0) {
    float s = 0.0f;
    for (int i = 0; i < DIM; ++i) s += red[i];
    kconst[k] = -s;  // == -0.5*logdet
  }
  // emit W fragments: d = t&127 (row of W), h = t>>7
  {
    const int d = t & 127, h = t >> 7;
#pragma unroll
    for (int es = 0; es < 8; ++es) {
      float v[8];
#pragma unroll
      for (int j = 0; j < 8; ++j) v[j] = Wv[d][es * 16 + h * 8 + j];
      int4 hi, lo;
      SPLIT_PACK(v[0], v[1], v[2], v[3], v[4], v[5], v[6], v[7], hi, lo)
      const size_t idx = ((size_t)(k * 8 + es) * DIM + d) * 2 + h;
      WBh[idx] = hi;
      WBl[idx] = lo;
    }
  }
}

// ---------------------------------------------------------------------------
// estep: Y = X*W_k^T via MFMA (3-pass bf16 split), maha = ||Y - m||^2,
// softmax over k.  Block = 256 thr (4 waves x 32 n-rows = 128 rows).
// Writes Z[n][k] (output) AND Zt[k][n] (transposed, for gram).
// ---------------------------------------------------------------------------
#define EST_DT(DT)                                                            \
  {                                                                           \
    f32x16 accv;                                                              \
    _Pragma("unroll") for (int r = 0; r < 16; ++r) accv[r] = 0.0f;            \
    _Pragma("unroll") for (int es = 0; es < 2 * (DT) + 2; ++es) {             \
      const size_t wb = ((size_t)(k * 8 + es) * DIM + (DT) * 32 + c31) * 2 + hh; \
      const int4 bh = WBh[wb];                                                \
      const int4 bl = WBl[wb];                                                \
      accv = __builtin_amdgcn_mfma_f32_32x32x16_bf16(bc(axl[es]), bc(bh), accv, 0, 0, 0); \
      accv = __builtin_amdgcn_mfma_f32_32x32x16_bf16(bc(axh[es]), bc(bl), accv, 0, 0, 0); \
      accv = __builtin_amdgcn_mfma_f32_32x32x16_bf16(bc(axh[es]), bc(bh), accv, 0, 0, 0); \
    }                                                                         \
    const float mval = mvec[k * DIM + (DT) * 32 + c31];                       \
    _Pragma("unroll") for (int r = 0; r < 16; ++r) {                          \
      const float v = accv[r] - mval;                                         \
      part[r] = fmaf(v, v, part[r]);                                          \
    }                                                                         \
  }

__global__ __launch_bounds__(256, 2) void estep_kernel(
    const float* __restrict__ X, const int4* __restrict__ WBh,
    const int4* __restrict__ WBl, const float* __restrict__ mvec,
    const float* __restrict__ kconst, float* __restrict__ Z,
    float* __restrict__ Zt)
{
  __shared__ int4 XAh[8][128][2];  // 32KB  (A frags hi) — lp aliases this
  __shared__ int4 XAl[8][128][2];  // 32KB  (A frags lo)
  float (*lp)[KC + 1] = (float (*)[KC + 1]) & XAh[0][0][0];  // 128x17 = 8.5KB

  const int tid = threadIdx.x;
  const int c31 = tid & 31;
  const int hh = (tid & 63) >> 5;
  const int w = tid >> 6;
  const size_t n0 = (size_t)blockIdx.x * 128;

  // stage X fragments: thread (n = tid&127, h2 = tid>>7), 8 es each
  {
    const int n = tid & 127, h2 = tid >> 7;
    const int hsw = h2 ^ ((n >> 2) & 1);  // LDS h-slot swizzle
    const float4* xr = (const float4*)(X + (n0 + n) * DIM);
#pragma unroll
    for (int es = 0; es < 8; ++es) {
      const float4 a = xr[es * 4 + h2 * 2];
      const float4 b = xr[es * 4 + h2 * 2 + 1];
      int4 hi, lo;
      SPLIT_PACK(a.x, a.y, a.z, a.w, b.x, b.y, b.z, b.w, hi, lo)
      XAh[es][n][hsw] = hi;
      XAl[es][n][hsw] = lo;
    }
  }
  __syncthreads();

  // preload this wave's A fragments (rows w*32 + c31), reused for all k
  int4 axh[8], axl[8];
  {
    const int nl = w * 32 + c31;
    const int hsw = hh ^ ((nl >> 2) & 1);
#pragma unroll
    for (int es = 0; es < 8; ++es) {
      axh[es] = XAh[es][nl][hsw];
      axl[es] = XAl[es][nl][hsw];
    }
  }
  __syncthreads();  // XAh now dead -> lp may be written

  for (int k = 0; k < KC; ++k) {
    float part[16];
#pragma unroll
    for (int r = 0; r < 16; ++r) part[r] = 0.0f;
    EST_DT(0)
    EST_DT(1)
    EST_DT(2)
    EST_DT(3)
    // reduce across the 32 cols (halves stay separate: masks < 32)
#pragma unroll
    for (int off = 1; off < 32; off <<= 1) {
#pragma unroll
      for (int r = 0; r < 16; ++r) part[r] += __shfl_xor(part[r], off, 64);
    }
    float sel = 0.0f;
#pragma unroll
    for (int r = 0; r < 16; ++r) sel = (c31 == r) ? part[r] : sel;
    if (c31 < 16) {
      const int row = (c31 & 3) + 8 * (c31 >> 2) + 4 * hh;
      lp[w * 32 + row][k] = kconst[k] - 0.5f * sel;
    }
  }
  __syncthreads();

  if (tid < 128) {
    float v[KC];
    float mx = -1e30f;
#pragma unroll
    for (int q = 0; q < KC; ++q) { v[q] = lp[tid][q]; mx = fmaxf(mx, v[q]); }
    float s = 0.0f;
#pragma unroll
    for (int q = 0; q < KC; ++q) { v[q] = expf(v[q] - mx); s += v[q]; }
    const float inv = 1.0f / s;
    float4* zr = (float4*)(Z + (n0 + tid) * KC);
#pragma unroll
    for (int q = 0; q < KC / 4; ++q)
      zr[q] = make_float4(v[4 * q] * inv, v[4 * q + 1] * inv,
                          v[4 * q + 2] * inv, v[4 * q + 3] * inv);
    // transposed copy for gram (coalesced across tid per k)
#pragma unroll
    for (int q = 0; q < KC; ++q)
      Zt[(size_t)q * NPTS + n0 + tid] = v[q] * inv;
  }
}

// ---------------------------------------------------------------------------
// gram v3 (LDS-free): G_k[d][e] = sum_n (z_k x)_d x_e via MFMA.
// Block (k, ch, dh) = 4 waves; wave w: dt=w&1, et0=(w>>1)*2.
// A-frag built IN REGISTERS per 16-n step: lane (c31,hh) loads XB[nb][drd][hh]
// (8 n-packed x values of its column), z from Zt (contiguous), multiplies,
// splits hi/lo.  B-frags straight from XB.  No LDS, no barriers.
// ---------------------------------------------------------------------------
__global__ __launch_bounds__(256, 4) void gram_kernel(
    const float* __restrict__ Zt, const int4* __restrict__ XBh,
    const int4* __restrict__ XBl, float* __restrict__ Gp,
    float* __restrict__ sp, float* __restrict__ twp)
{
  const int k = blockIdx.x;
  const int ch = blockIdx.y;
  const int dh = blockIdx.z;
  const int tid = threadIdx.x;
  const int c31 = tid & 31;
  const int hh = (tid & 63) >> 5;
  const int w = tid >> 6;
  const int dt = w & 1;
  const int et0 = (w >> 1) * 2;
  const int drd = dh * 64 + dt * 32 + c31;   // this lane's A column (d)
  const int n0 = ch * GCH;
  const float* __restrict__ zrow = Zt + (size_t)k * NPTS;

  f32x16 acc0, acc1;
#pragma unroll
  for (int r = 0; r < 16; ++r) { acc0[r] = 0.0f; acc1[r] = 0.0f; }
  float sacc = 0.0f, twacc = 0.0f;

#pragma unroll 2
  for (int nb = 0; nb < GCH / 16; ++nb) {
    const size_t nb16 = (size_t)(ch * (GCH / 16)) + nb;
    // ---- A-frag: x column drd for this hh's 8 n, times z ----
    const size_t ai = (nb16 * DIM + drd) * 2 + hh;
    const int4 xh = XBh[ai];
    const int4 xl = XBl[ai];
    const float4 z0 = *(const float4*)(zrow + n0 + nb * 16 + hh * 8);
    const float4 z1 = *(const float4*)(zrow + n0 + nb * 16 + hh * 8 + 4);
    float p[8];
    {
      const unsigned wx0 = (unsigned)xh.x, wl0 = (unsigned)xl.x;
      const unsigned wx1 = (unsigned)xh.y, wl1 = (unsigned)xl.y;
      const unsigned wx2 = (unsigned)xh.z, wl2 = (unsigned)xl.z;
      const unsigned wx3 = (unsigned)xh.w, wl3 = (unsigned)xl.w;
      p[0] = z0.x * (__uint_as_float(wx0 << 16) + __uint_as_float(wl0 << 16));
      p[1] = z0.y * (__uint_as_float(wx0 & 0xffff0000u) + __uint_as_float(wl0 & 0xffff0000u));
      p[2] = z0.z * (__uint_as_float(wx1 << 16) + __uint_as_float(wl1 << 16));
      p[3] = z0.w * (__uint_as_float(wx1 & 0xffff0000u) + __uint_as_float(wl1 & 0xffff0000u));
      p[4] = z1.x * (__uint_as_float(wx2 << 16) + __uint_as_float(wl2 << 16));
      p[5] = z1.y * (__uint_as_float(wx2 & 0xffff0000u) + __uint_as_float(wl2 & 0xffff0000u));
      p[6] = z1.z * (__uint_as_float(wx3 << 16) + __uint_as_float(wl3 << 16));
      p[7] = z1.w * (__uint_as_float(wx3 & 0xffff0000u) + __uint_as_float(wl3 & 0xffff0000u));
    }
    sacc += ((p[0] + p[1]) + (p[2] + p[3])) + ((p[4] + p[5]) + (p[6] + p[7]));
    twacc += ((z0.x + z0.y) + (z0.z + z0.w)) + ((z1.x + z1.y) + (z1.z + z1.w));
    int4 ah, al;
    SPLIT_PACK(p[0], p[1], p[2], p[3], p[4], p[5], p[6], p[7], ah, al)
    // ---- B-frags + MFMA ----
    const size_t b0 = (nb16 * DIM + (et0 + 0) * 32 + c31) * 2 + hh;
    const size_t b1 = (nb16 * DIM + (et0 + 1) * 32 + c31) * 2 + hh;
    {
      const int4 bh = XBh[b0], bl = XBl[b0];
      acc0 = __builtin_amdgcn_mfma_f32_32x32x16_bf16(bc(al), bc(bh), acc0, 0, 0, 0);
      acc0 = __builtin_amdgcn_mfma_f32_32x32x16_bf16(bc(ah), bc(bl), acc0, 0, 0, 0);
      acc0 = __builtin_amdgcn_mfma_f32_32x32x16_bf16(bc(ah), bc(bh), acc0, 0, 0, 0);
    }
    {
      const int4 bh = XBh[b1], bl = XBl[b1];
      acc1 = __builtin_amdgcn_mfma_f32_32x32x16_bf16(bc(al), bc(bh), acc1, 0, 0, 0);
      acc1 = __builtin_amdgcn_mfma_f32_32x32x16_bf16(bc(ah), bc(bl), acc1, 0, 0, 0);
      acc1 = __builtin_amdgcn_mfma_f32_32x32x16_bf16(bc(ah), bc(bh), acc1, 0, 0, 0);
    }
  }

  // store G tiles: d = dh*64 + dt*32 + row(reg), e = (et0+ei)*32 + c31
  {
    float* gbase = Gp + (size_t)(ch * KC + k) * (DIM * DIM);
#pragma unroll
    for (int r = 0; r < 16; ++r) {
      const int row = (r & 3) + 8 * (r >> 2) + 4 * hh;
      const int d = dh * 64 + dt * 32 + row;
      gbase[(size_t)d * DIM + (et0 + 0) * 32 + c31] = acc0[r];
      gbase[(size_t)d * DIM + (et0 + 1) * 32 + c31] = acc1[r];
    }
  }

  // first moment: combine the two hh-halves (same drd), write from waves 0,1
  sacc += __shfl_xor(sacc, 32, 64);
  if (w < 2 && hh == 0)
    sp[(size_t)(ch * KC + k) * DIM + dt * 32 + c31 + dh * 64] = sacc;
  // total weight (identical across c31): combine hh halves, one writer
  twacc += __shfl_xor(twacc, 32, 64);
  if (dh == 0 && tid == 0) twp[ch * KC + k] = twacc;
}

__global__ __launch_bounds__(256) void reduce_means_kernel(
    const float* __restrict__ sp, const float* __restrict__ twp,
    float* __restrict__ means, float* __restrict__ tw_out)
{
  const int idx = blockIdx.x * 256 + threadIdx.x;  // k*128 + d
  const int k = idx >> 7;
  float tw = 0.0f;
#pragma unroll
  for (int c = 0; c < NCHG; ++c) tw += twp[c * KC + k];
  float s = 0.0f;
  for (int c = 0; c < NCHG; ++c) s += sp[(size_t)c * KC * DIM + idx];
  means[idx] = s / (tw + EPS_C);
  if ((idx & 127) == 0) tw_out[k] = tw;
}

// cov = G/(tw+eps) - ((tw+2eps)/(tw+eps)) * mu mu^T  (exact expansion)
__global__ __launch_bounds__(256) void finalize_cov_kernel(
    const float* __restrict__ Gp, const float* __restrict__ means,
    const float* __restrict__ tw_in, float* __restrict__ covs)
{
  const int idx = blockIdx.x * 256 + threadIdx.x;  // k*16384 + d*128 + e
  const int k = idx >> 14;
  const int d = (idx >> 7) & 127;
  const int e = idx & 127;
  float g = 0.0f;
  for (int c = 0; c < NCHG; ++c)
    g += Gp[(size_t)(c * KC + k) * (DIM * DIM) + d * DIM + e];
  const float tw = tw_in[k];
  const float denom = tw + EPS_C;
  const float md = means[k * DIM + d], me = means[k * DIM + e];
  covs[idx] = g / denom - ((tw + 2.0f * EPS_C) / denom) * md * me;
}

__global__ __launch_bounds__(256) void out_kernel(
    const float* __restrict__ X, const float* __restrict__ Z,
    const float* __restrict__ means, float* __restrict__ out)
{
  const int i4 = blockIdx.x * 256 + threadIdx.x;  // float4 index
  const int n = i4 >> 5;
  const int q = i4 & 31;
  float4 acc = ((const float4*)X)[i4];
  const float* zr = Z + (size_t)n * KC;
#pragma unroll
  for (int k = 0; k < KC; ++k) {
    const float zk = BETA_C * zr[k];
    const float4 mu = ((const float4*)means)[k * 32 + q];
    acc.x = fmaf(zk, mu.x, acc.x);
    acc.y = fmaf(zk, mu.y, acc.y);
    acc.z = fmaf(zk, mu.z, acc.z);
    acc.w = fmaf(zk, mu.w, acc.w);
  }
  ((float4*)out)[i4] = acc;
}

// ---------------------------------------------------------------------------
extern "C" void kernel_launch(void* const* d_in, const int* in_sizes, int n_in,
                              void* d_out, int out_size, void* d_ws, size_t ws_size,
                              hipStream_t stream)
{
  const float* X = (const float*)d_in[0];       // [65536,128]
  const float* means0 = (const float*)d_in[1];  // [16,128]
  const float* covs0 = (const float*)d_in[2];   // [16,128,128]
  float* out = (float*)d_out;                   // [65536,128]
  float* Zout = out + (size_t)NPTS * DIM;       // [65536,16] second output

  // XB fragments live in the d_out "out" region (32 MiB, exactly fits):
  // only out_kernel (the last launch) writes `out`, and it never reads XB.
  int4* XBh = (int4*)out;                                 // 16 MiB
  int4* XBl = XBh + (size_t)(NPTS / 16) * DIM * 2;        // 16 MiB

  // workspace (bytes): ~23 MB total (known-good budget is >= 26.3 MB)
  char* p = (char*)d_ws;
  float* covs_cur  = (float*)p;  p += (size_t)262144 * 4;          // 1MB
  float* mvec      = (float*)p;  p += 2048 * 4;
  float* kconst    = (float*)p;  p += 64;
  float* tw        = (float*)p;  p += 64;
  float* means_cur = (float*)p;  p += 2048 * 4;
  float* sp        = (float*)p;  p += (size_t)NCHG * KC * DIM * 4; // 128KB
  float* twp       = (float*)p;  p += NCHG * KC * 4;
  int4* WBh        = (int4*)p;   p += (size_t)KC * 8 * DIM * 2 * 16;   // 512KB
  int4* WBl        = (int4*)p;   p += (size_t)KC * 8 * DIM * 2 * 16;   // 512KB
  float* Zt        = (float*)p;  p += (size_t)KC * NPTS * 4;           // 4MB
  float* Gp        = (float*)p;  p += (size_t)NCHG * KC * DIM * DIM * 4;  // 16.8MB

  const int prep_lds = 37312 * 4;  // 149,248 B dynamic LDS
  (void)hipFuncSetAttribute((const void*)prep_kernel,
      hipFuncAttributeMaxDynamicSharedMemorySize, prep_lds);

  xsplit_kernel<<<NPTS / 16, 256, 0, stream>>>(X, XBh, XBl);

  for (int s = 0; s < STAGES; ++s) {
    const float* cs = (s == 0) ? covs0 : covs_cur;
    const float* ms = (s == 0) ? means0 : means_cur;
    prep_kernel<<<KC, 256, prep_lds, stream>>>(cs, ms, WBh, WBl, mvec, kconst);
    estep_kernel<<<NPTS / 128, 256, 0, stream>>>(X, WBh, WBl, mvec, kconst,
                                                 Zout, Zt);
    gram_kernel<<<dim3(KC, NCHG, 2), 256, 0, stream>>>(Zt, XBh, XBl, Gp, sp, twp);
    reduce_means_kernel<<<8, 256, 0, stream>>>(sp, twp, means_cur, tw);
    if (s < STAGES - 1)
      finalize_cov_kernel<<<KC * DIM * DIM / 256, 256, 0, stream>>>(
          Gp, means_cur, tw, covs_cur);
  }
  out_kernel<<<(NPTS * DIM / 4) / 256, 256, 0, stream>>>(X, Zout, means_cur, out);
}

// Round 8
// 5316.229 us; speedup vs baseline: 5.6714x; 1.1069x over previous
//
#include <hip/hip_runtime.h>
#include <math.h>

// GMM EM, 10 stages, N=65536 D=128 K=16, fp32 in/out.
// v5: gram restructured: wave = d-tile covering ALL 4 e-tiles (split cost
//     amortized over 12 MFMAs), v_cvt_pk_bf16_f32 product-split (24 ops vs
//     ~90), single shared Gp with epilogue atomics (NCHG 32 -> 8 waves/CU),
//     stage-10 gram replaced by cheap moment kernel.
// Consistency rule: A and B fragments always packed with the SAME
// (lane-half h = lane>>5, j) -> k map (k = h*8 + j). C/D layout: col=lane&31,
// row=(reg&3)+8*(reg>>2)+4*(lane>>5)  [validated by v3.2/v4 passes].
// 2-term split note: lo = p - hi_f is exact (Sterbenz), so hi's rounding
// mode is irrelevant -> cvt_pk(A) mixed with C-packed(B) is safe.

#define NPTS 65536
#define DIM 128
#define KC 16
#define STAGES 10
#define BETA_C 3.0f
#define EPS_C 1e-6f
#define NCHG 32
#define GCH (NPTS / NCHG)   // 2048 n per gram chunk

typedef __attribute__((ext_vector_type(8))) short bfrag_t;   // 8 bf16
typedef __attribute__((ext_vector_type(16))) float f32x16;

__device__ __forceinline__ unsigned short bf_hi(float f) {
  unsigned u = __float_as_uint(f);
  return (unsigned short)((u + 0x7fffu + ((u >> 16) & 1u)) >> 16);  // RNE
}
__device__ __forceinline__ float bf_f(unsigned short h) {
  return __uint_as_float((unsigned)h << 16);
}
__device__ __forceinline__ bfrag_t bc(int4 v) {
  return __builtin_bit_cast(bfrag_t, v);
}

// split 8 fp32 into hi/lo bf16 int4-packs (k = h*8+j order preserved) — C path
#define SPLIT_PACK(V0, V1, V2, V3, V4, V5, V6, V7, HI, LO)                    \
  {                                                                           \
    const unsigned short h0 = bf_hi(V0), h1 = bf_hi(V1), h2 = bf_hi(V2),      \
                         h3 = bf_hi(V3), h4 = bf_hi(V4), h5 = bf_hi(V5),      \
                         h6 = bf_hi(V6), h7 = bf_hi(V7);                      \
    (HI).x = (int)((unsigned)h0 | ((unsigned)h1 << 16));                      \
    (HI).y = (int)((unsigned)h2 | ((unsigned)h3 << 16));                      \
    (HI).z = (int)((unsigned)h4 | ((unsigned)h5 << 16));                      \
    (HI).w = (int)((unsigned)h6 | ((unsigned)h7 << 16));                      \
    const unsigned short l0 = bf_hi((V0) - bf_f(h0)),                         \
                         l1 = bf_hi((V1) - bf_f(h1)),                         \
                         l2 = bf_hi((V2) - bf_f(h2)),                         \
                         l3 = bf_hi((V3) - bf_f(h3)),                         \
                         l4 = bf_hi((V4) - bf_f(h4)),                         \
                         l5 = bf_hi((V5) - bf_f(h5)),                         \
                         l6 = bf_hi((V6) - bf_f(h6)),                         \
                         l7 = bf_hi((V7) - bf_f(h7));                         \
    (LO).x = (int)((unsigned)l0 | ((unsigned)l1 << 16));                      \
    (LO).y = (int)((unsigned)l2 | ((unsigned)l3 << 16));                      \
    (LO).z = (int)((unsigned)l4 | ((unsigned)l5 << 16));                      \
    (LO).w = (int)((unsigned)l6 | ((unsigned)l7 << 16));                      \
  }

// fast split via v_cvt_pk_bf16_f32 (gfx950; guide T12 recipe).
__device__ __forceinline__ int cvt_pk2(float a, float b) {
  int r;
  asm("v_cvt_pk_bf16_f32 %0, %1, %2" : "=v"(r) : "v"(a), "v"(b));
  return r;  // low16 = bf16(a), high16 = bf16(b)
}
__device__ __forceinline__ void cvt_split2(float a, float b, int& hi, int& lo) {
  hi = cvt_pk2(a, b);
  const float fa = __uint_as_float((unsigned)hi << 16);
  const float fb = __uint_as_float((unsigned)hi & 0xffff0000u);
  lo = cvt_pk2(a - fa, b - fb);
}

// ---------------------------------------------------------------------------
// xsplit (once per launch): X bf16 hi/lo in B-fragment layout
// XB[nb][e][h] int4 ; element j is n = nb*16 + h*8 + j, column e.
// ---------------------------------------------------------------------------
__global__ __launch_bounds__(256) void xsplit_kernel(
    const float* __restrict__ X, int4* __restrict__ XBh, int4* __restrict__ XBl)
{
  const int nb = blockIdx.x;
  const int t = threadIdx.x;
  const int e = t >> 1, h = t & 1;
  float v[8];
#pragma unroll
  for (int j = 0; j < 8; ++j)
    v[j] = X[(size_t)(nb * 16 + h * 8 + j) * DIM + e];
  int4 hi, lo;
  SPLIT_PACK(v[0], v[1], v[2], v[3], v[4], v[5], v[6], v[7], hi, lo)
  const size_t idx = ((size_t)nb * DIM + e) * 2 + h;
  XBh[idx] = hi;
  XBl[idx] = lo;
}

// ---------------------------------------------------------------------------
// prep: blocked Cholesky (NB=16) of (cov+eps I), blocked triangular inverse
// W=L^-1, m=W*mu, kconst=-0.5*logdet; emits W as estep-B fragments.
// ---------------------------------------------------------------------------
__global__ __launch_bounds__(256) void prep_kernel(
    const float* __restrict__ covs, const float* __restrict__ means,
    int4* __restrict__ WBh, int4* __restrict__ WBl,
    float* __restrict__ mvec, float* __restrict__ kconst)
{
  extern __shared__ float smem[];
  float (*A)[DIM + 1]  = (float (*)[DIM + 1])smem;            // 128*129
  float (*Wv)[DIM + 1] = (float (*)[DIM + 1])(smem + 16512);  // 128*129
  float (*T)[65]       = (float (*)[65])(smem + 33024);       // 64*65
  float* red = smem + 37184;                                  // 128

  const int k = blockIdx.x;
  const int t = threadIdx.x;
  const int lane = t & 63;
  const int wv = t >> 6;
  const float* C = covs + (size_t)k * DIM * DIM;

  {
    const int tr = t & 127, th = t >> 7;
    for (int i = th; i < DIM; i += 2) {
      float v = C[(size_t)i * DIM + tr];
      if (i == tr) v += EPS_C;
      A[i][tr] = v;
      Wv[i][tr] = 0.0f;
    }
  }
  __syncthreads();

  for (int b = 0; b < 8; ++b) {
    const int o = b * 16;
    if (wv == 0) {
      const int l = lane;
      for (int j = 0; j < 16; ++j) {
        const float djj = sqrtf(A[o + j][o + j]);
        if (l == j) A[o + j][o + j] = djj;
        if (l > j && l < 16) {
          A[o + l][o + j] /= djj;
          const float f = A[o + l][o + j];
          for (int c = j + 1; c <= l; ++c)
            A[o + l][o + c] -= f * A[o + c][o + j];
        }
      }
    }
    __syncthreads();
    const int nr = DIM - o - 16;
    if (nr > 0) {
      if (t < nr) {
        const int i = o + 16 + t;
        float li[16];
#pragma unroll
        for (int c = 0; c < 16; ++c) {
          float s = A[i][o + c];
#pragma unroll
          for (int p = 0; p < c; ++p) s -= li[p] * A[o + c][o + p];
          li[c] = s / A[o + c][o + c];
          A[i][o + c] = li[c];
        }
      }
      __syncthreads();
      {
        const int ir = t >> 1, half = t & 1;
        if (ir < nr) {
          const int i = o + 16 + ir;
          float li[16];
#pragma unroll
          for (int p = 0; p < 16; ++p) li[p] = A[i][o + p];
          for (int j = o + 16 + half; j <= i; j += 2) {
            float s = A[i][j];
#pragma unroll
            for (int p = 0; p < 16; ++p) s -= li[p] * A[j][o + p];
            A[i][j] = s;
          }
        }
      }
      __syncthreads();
    }
  }

  if (t < DIM) {
    const int g = t >> 6, c = t & 63, o = g * 64;
    Wv[o + c][o + c] = 1.0f / A[o + c][o + c];
    for (int i = c + 1; i < 64; ++i) {
      float s = 0.0f;
      for (int p = c; p < i; ++p) s += A[o + i][o + p] * Wv[o + p][o + c];
      Wv[o + i][o + c] = -s / A[o + i][o + i];
    }
  }
  __syncthreads();
  for (int idx = t; idx < 4096; idx += 256) {
    const int i = idx >> 6, c = idx & 63;
    float s = 0.0f;
    for (int p = c; p < 64; ++p) s += A[64 + i][p] * Wv[p][c];
    T[i][c] = s;
  }
  __syncthreads();
  for (int idx = t; idx < 4096; idx += 256) {
    const int i = idx >> 6, c = idx & 63;
    float s = 0.0f;
    for (int p = 0; p <= i; ++p) s += Wv[64 + i][64 + p] * T[p][c];
    Wv[64 + i][c] = -s;
  }
  __syncthreads();

  if (t < DIM) {
    const float* mu = means + k * DIM;
    float s = 0.0f;
    for (int e = 0; e <= t; ++e) s += Wv[t][e] * mu[e];
    mvec[k * DIM + t] = s;
    red[t] = logf(A[t][t]);
  }
  __syncthreads();
  if (t == 0) {
    float s = 0.0f;
    for (int i = 0; i < DIM; ++i) s += red[i];
    kconst[k] = -s;  // == -0.5*logdet
  }
  {
    const int d = t & 127, h = t >> 7;
#pragma unroll
    for (int es = 0; es < 8; ++es) {
      float v[8];
#pragma unroll
      for (int j = 0; j < 8; ++j) v[j] = Wv[d][es * 16 + h * 8 + j];
      int4 hi, lo;
      SPLIT_PACK(v[0], v[1], v[2], v[3], v[4], v[5], v[6], v[7], hi, lo)
      const size_t idx = ((size_t)(k * 8 + es) * DIM + d) * 2 + h;
      WBh[idx] = hi;
      WBl[idx] = lo;
    }
  }
}

// ---------------------------------------------------------------------------
// estep: Y = X*W_k^T via MFMA (3-pass bf16 split), maha = ||Y - m||^2,
// softmax over k.  Block = 256 thr (4 waves x 32 n-rows = 128 rows).
// Writes Z[n][k] (output) AND Zt[k][n] (transposed, for gram/moment).
// ---------------------------------------------------------------------------
#define EST_DT(DT)                                                            \
  {                                                                           \
    f32x16 accv;                                                              \
    _Pragma("unroll") for (int r = 0; r < 16; ++r) accv[r] = 0.0f;            \
    _Pragma("unroll") for (int es = 0; es < 2 * (DT) + 2; ++es) {             \
      const size_t wb = ((size_t)(k * 8 + es) * DIM + (DT) * 32 + c31) * 2 + hh; \
      const int4 bh = WBh[wb];                                                \
      const int4 bl = WBl[wb];                                                \
      accv = __builtin_amdgcn_mfma_f32_32x32x16_bf16(bc(axl[es]), bc(bh), accv, 0, 0, 0); \
      accv = __builtin_amdgcn_mfma_f32_32x32x16_bf16(bc(axh[es]), bc(bl), accv, 0, 0, 0); \
      accv = __builtin_amdgcn_mfma_f32_32x32x16_bf16(bc(axh[es]), bc(bh), accv, 0, 0, 0); \
    }                                                                         \
    const float mval = mvec[k * DIM + (DT) * 32 + c31];                       \
    _Pragma("unroll") for (int r = 0; r < 16; ++r) {                          \
      const float v = accv[r] - mval;                                         \
      part[r] = fmaf(v, v, part[r]);                                          \
    }                                                                         \
  }

__global__ __launch_bounds__(256, 2) void estep_kernel(
    const float* __restrict__ X, const int4* __restrict__ WBh,
    const int4* __restrict__ WBl, const float* __restrict__ mvec,
    const float* __restrict__ kconst, float* __restrict__ Z,
    float* __restrict__ Zt)
{
  __shared__ int4 XAh[8][128][2];  // 32KB  (A frags hi) — lp aliases this
  __shared__ int4 XAl[8][128][2];  // 32KB  (A frags lo)
  float (*lp)[KC + 1] = (float (*)[KC + 1]) & XAh[0][0][0];  // 128x17 = 8.5KB

  const int tid = threadIdx.x;
  const int c31 = tid & 31;
  const int hh = (tid & 63) >> 5;
  const int w = tid >> 6;
  const size_t n0 = (size_t)blockIdx.x * 128;

  {
    const int n = tid & 127, h2 = tid >> 7;
    const int hsw = h2 ^ ((n >> 2) & 1);  // LDS h-slot swizzle
    const float4* xr = (const float4*)(X + (n0 + n) * DIM);
#pragma unroll
    for (int es = 0; es < 8; ++es) {
      const float4 a = xr[es * 4 + h2 * 2];
      const float4 b = xr[es * 4 + h2 * 2 + 1];
      int4 hi, lo;
      SPLIT_PACK(a.x, a.y, a.z, a.w, b.x, b.y, b.z, b.w, hi, lo)
      XAh[es][n][hsw] = hi;
      XAl[es][n][hsw] = lo;
    }
  }
  __syncthreads();

  int4 axh[8], axl[8];
  {
    const int nl = w * 32 + c31;
    const int hsw = hh ^ ((nl >> 2) & 1);
#pragma unroll
    for (int es = 0; es < 8; ++es) {
      axh[es] = XAh[es][nl][hsw];
      axl[es] = XAl[es][nl][hsw];
    }
  }
  __syncthreads();  // XAh now dead -> lp may be written

  for (int k = 0; k < KC; ++k) {
    float part[16];
#pragma unroll
    for (int r = 0; r < 16; ++r) part[r] = 0.0f;
    EST_DT(0)
    EST_DT(1)
    EST_DT(2)
    EST_DT(3)
#pragma unroll
    for (int off = 1; off < 32; off <<= 1) {
#pragma unroll
      for (int r = 0; r < 16; ++r) part[r] += __shfl_xor(part[r], off, 64);
    }
    float sel = 0.0f;
#pragma unroll
    for (int r = 0; r < 16; ++r) sel = (c31 == r) ? part[r] : sel;
    if (c31 < 16) {
      const int row = (c31 & 3) + 8 * (c31 >> 2) + 4 * hh;
      lp[w * 32 + row][k] = kconst[k] - 0.5f * sel;
    }
  }
  __syncthreads();

  if (tid < 128) {
    float v[KC];
    float mx = -1e30f;
#pragma unroll
    for (int q = 0; q < KC; ++q) { v[q] = lp[tid][q]; mx = fmaxf(mx, v[q]); }
    float s = 0.0f;
#pragma unroll
    for (int q = 0; q < KC; ++q) { v[q] = expf(v[q] - mx); s += v[q]; }
    const float inv = 1.0f / s;
    float4* zr = (float4*)(Z + (n0 + tid) * KC);
#pragma unroll
    for (int q = 0; q < KC / 4; ++q)
      zr[q] = make_float4(v[4 * q] * inv, v[4 * q + 1] * inv,
                          v[4 * q + 2] * inv, v[4 * q + 3] * inv);
#pragma unroll
    for (int q = 0; q < KC; ++q)
      Zt[(size_t)q * NPTS + n0 + tid] = v[q] * inv;
  }
}

// ---------------------------------------------------------------------------
// gram v5: G_k[d][e] = sum_n (z_k x)_d x_e via MFMA.
// Block (k, ch) = 4 waves; wave w = d-tile (dt=w), loops ALL 4 e-tiles
// (one A-split feeds 12 MFMAs). cvt_pk split. Epilogue atomicAdd into the
// single shared Gp[k] (zeroed per stage by hipMemsetAsync). No LDS/barriers.
// ---------------------------------------------------------------------------
#define GR_ET(ACC, ET)                                                        \
  {                                                                           \
    const size_t bi = (nbg * DIM + (ET) * 32 + c31) * 2 + hh;                 \
    const int4 bh = XBh[bi], bl = XBl[bi];                                    \
    ACC = __builtin_amdgcn_mfma_f32_32x32x16_bf16(bc(al), bc(bh), ACC, 0, 0, 0); \
    ACC = __builtin_amdgcn_mfma_f32_32x32x16_bf16(bc(ah), bc(bl), ACC, 0, 0, 0); \
    ACC = __builtin_amdgcn_mfma_f32_32x32x16_bf16(bc(ah), bc(bh), ACC, 0, 0, 0); \
  }

__global__ __launch_bounds__(256, 2) void gram_kernel(
    const float* __restrict__ Zt, const int4* __restrict__ XBh,
    const int4* __restrict__ XBl, float* __restrict__ Gp,
    float* __restrict__ sp, float* __restrict__ twp)
{
  const int k = blockIdx.x;
  const int ch = blockIdx.y;
  const int tid = threadIdx.x;
  const int c31 = tid & 31;
  const int hh = (tid & 63) >> 5;
  const int w = tid >> 6;
  const int drd = w * 32 + c31;            // this lane's A column (d)
  const float* __restrict__ zrow = Zt + (size_t)k * NPTS + ch * GCH;

  f32x16 acc0, acc1, acc2, acc3;
#pragma unroll
  for (int r = 0; r < 16; ++r) { acc0[r] = 0.f; acc1[r] = 0.f; acc2[r] = 0.f; acc3[r] = 0.f; }
  float sacc = 0.0f, twacc = 0.0f;

#pragma unroll 2
  for (int nb = 0; nb < GCH / 16; ++nb) {
    const size_t nbg = (size_t)(ch * (GCH / 16)) + nb;
    // A-frag: x column drd for this hh's 8 n, times z
    const size_t ai = (nbg * DIM + drd) * 2 + hh;
    const int4 xh = XBh[ai];
    const int4 xl = XBl[ai];
    const float4 z0 = *(const float4*)(zrow + nb * 16 + hh * 8);
    const float4 z1 = *(const float4*)(zrow + nb * 16 + hh * 8 + 4);
    float p0, p1, p2, p3, p4, p5, p6, p7;
    {
      const unsigned a0 = (unsigned)xh.x, b0 = (unsigned)xl.x;
      const unsigned a1 = (unsigned)xh.y, b1 = (unsigned)xl.y;
      const unsigned a2 = (unsigned)xh.z, b2 = (unsigned)xl.z;
      const unsigned a3 = (unsigned)xh.w, b3 = (unsigned)xl.w;
      p0 = z0.x * (__uint_as_float(a0 << 16) + __uint_as_float(b0 << 16));
      p1 = z0.y * (__uint_as_float(a0 & 0xffff0000u) + __uint_as_float(b0 & 0xffff0000u));
      p2 = z0.z * (__uint_as_float(a1 << 16) + __uint_as_float(b1 << 16));
      p3 = z0.w * (__uint_as_float(a1 & 0xffff0000u) + __uint_as_float(b1 & 0xffff0000u));
      p4 = z1.x * (__uint_as_float(a2 << 16) + __uint_as_float(b2 << 16));
      p5 = z1.y * (__uint_as_float(a2 & 0xffff0000u) + __uint_as_float(b2 & 0xffff0000u));
      p6 = z1.z * (__uint_as_float(a3 << 16) + __uint_as_float(b3 << 16));
      p7 = z1.w * (__uint_as_float(a3 & 0xffff0000u) + __uint_as_float(b3 & 0xffff0000u));
    }
    sacc += ((p0 + p1) + (p2 + p3)) + ((p4 + p5) + (p6 + p7));
    twacc += ((z0.x + z0.y) + (z0.z + z0.w)) + ((z1.x + z1.y) + (z1.z + z1.w));
    int4 ah, al;
    cvt_split2(p0, p1, ah.x, al.x);
    cvt_split2(p2, p3, ah.y, al.y);
    cvt_split2(p4, p5, ah.z, al.z);
    cvt_split2(p6, p7, ah.w, al.w);
    GR_ET(acc0, 0)
    GR_ET(acc1, 1)
    GR_ET(acc2, 2)
    GR_ET(acc3, 3)
  }

  // epilogue: atomic accumulate into shared G_k
  {
    float* gk = Gp + (size_t)k * (DIM * DIM);
#pragma unroll
    for (int r = 0; r < 16; ++r) {
      const int row = (r & 3) + 8 * (r >> 2) + 4 * hh;
      const int d = w * 32 + row;
      atomicAdd(&gk[(size_t)d * DIM + 0 * 32 + c31], acc0[r]);
      atomicAdd(&gk[(size_t)d * DIM + 1 * 32 + c31], acc1[r]);
      atomicAdd(&gk[(size_t)d * DIM + 2 * 32 + c31], acc2[r]);
      atomicAdd(&gk[(size_t)d * DIM + 3 * 32 + c31], acc3[r]);
    }
  }

  // first moment (combine hh halves; hh=0 lanes write 32 d per wave)
  sacc += __shfl_xor(sacc, 32, 64);
  if (hh == 0) sp[(size_t)(ch * KC + k) * DIM + drd] = sacc;
  if (w == 0) {
    twacc += __shfl_xor(twacc, 32, 64);
    if (tid == 0) twp[ch * KC + k] = twacc;
  }
}

// stage-10 M-step needs only means: first moments without the Gram
__global__ __launch_bounds__(128) void moment_kernel(
    const float* __restrict__ X, const float* __restrict__ Zt,
    float* __restrict__ sp, float* __restrict__ twp)
{
  __shared__ float red[128];
  const int k = blockIdx.x;
  const int ch = blockIdx.y;
  const int d = threadIdx.x;
  const int n0 = ch * GCH;
  const float* __restrict__ zrow = Zt + (size_t)k * NPTS;
  float s = 0.0f;
#pragma unroll 4
  for (int n = n0; n < n0 + GCH; ++n)
    s = fmaf(zrow[n], X[(size_t)n * DIM + d], s);
  sp[(size_t)(ch * KC + k) * DIM + d] = s;
  float tz = 0.0f;
  for (int i = 0; i < GCH / 128; ++i) tz += zrow[n0 + d + 128 * i];
  red[d] = tz;
  __syncthreads();
  if (d == 0) {
    float t = 0.0f;
    for (int i = 0; i < 128; ++i) t += red[i];
    twp[ch * KC + k] = t;
  }
}

__global__ __launch_bounds__(256) void reduce_means_kernel(
    const float* __restrict__ sp, const float* __restrict__ twp,
    float* __restrict__ means, float* __restrict__ tw_out)
{
  const int idx = blockIdx.x * 256 + threadIdx.x;  // k*128 + d
  const int k = idx >> 7;
  float tw = 0.0f;
#pragma unroll
  for (int c = 0; c < NCHG; ++c) tw += twp[c * KC + k];
  float s = 0.0f;
  for (int c = 0; c < NCHG; ++c) s += sp[(size_t)c * KC * DIM + idx];
  means[idx] = s / (tw + EPS_C);
  if ((idx & 127) == 0) tw_out[k] = tw;
}

// cov = G/(tw+eps) - ((tw+2eps)/(tw+eps)) * mu mu^T  (exact expansion)
__global__ __launch_bounds__(256) void finalize_cov_kernel(
    const float* __restrict__ Gp, const float* __restrict__ means,
    const float* __restrict__ tw_in, float* __restrict__ covs)
{
  const int idx = blockIdx.x * 256 + threadIdx.x;  // k*16384 + d*128 + e
  const int k = idx >> 14;
  const int d = (idx >> 7) & 127;
  const int e = idx & 127;
  const float g = Gp[idx];
  const float tw = tw_in[k];
  const float denom = tw + EPS_C;
  const float md = means[k * DIM + d], me = means[k * DIM + e];
  covs[idx] = g / denom - ((tw + 2.0f * EPS_C) / denom) * md * me;
}

__global__ __launch_bounds__(256) void out_kernel(
    const float* __restrict__ X, const float* __restrict__ Z,
    const float* __restrict__ means, float* __restrict__ out)
{
  const int i4 = blockIdx.x * 256 + threadIdx.x;  // float4 index
  const int n = i4 >> 5;
  const int q = i4 & 31;
  float4 acc = ((const float4*)X)[i4];
  const float* zr = Z + (size_t)n * KC;
#pragma unroll
  for (int k = 0; k < KC; ++k) {
    const float zk = BETA_C * zr[k];
    const float4 mu = ((const float4*)means)[k * 32 + q];
    acc.x = fmaf(zk, mu.x, acc.x);
    acc.y = fmaf(zk, mu.y, acc.y);
    acc.z = fmaf(zk, mu.z, acc.z);
    acc.w = fmaf(zk, mu.w, acc.w);
  }
  ((float4*)out)[i4] = acc;
}

// ---------------------------------------------------------------------------
extern "C" void kernel_launch(void* const* d_in, const int* in_sizes, int n_in,
                              void* d_out, int out_size, void* d_ws, size_t ws_size,
                              hipStream_t stream)
{
  const float* X = (const float*)d_in[0];       // [65536,128]
  const float* means0 = (const float*)d_in[1];  // [16,128]
  const float* covs0 = (const float*)d_in[2];   // [16,128,128]
  float* out = (float*)d_out;                   // [65536,128]
  float* Zout = out + (size_t)NPTS * DIM;       // [65536,16] second output

  // XB fragments live in the d_out "out" region (32 MiB, exactly fits):
  // only out_kernel (the last launch) writes `out`, and it never reads XB.
  int4* XBh = (int4*)out;                                 // 16 MiB
  int4* XBl = XBh + (size_t)(NPTS / 16) * DIM * 2;        // 16 MiB

  // workspace (bytes): ~7.8 MB total
  char* p = (char*)d_ws;
  float* covs_cur  = (float*)p;  p += (size_t)262144 * 4;          // 1MB
  float* mvec      = (float*)p;  p += 2048 * 4;
  float* kconst    = (float*)p;  p += 64;
  float* tw        = (float*)p;  p += 64;
  float* means_cur = (float*)p;  p += 2048 * 4;
  float* sp        = (float*)p;  p += (size_t)NCHG * KC * DIM * 4; // 256KB
  float* twp       = (float*)p;  p += NCHG * KC * 4;               // 2KB
  int4* WBh        = (int4*)p;   p += (size_t)KC * 8 * DIM * 2 * 16;   // 512KB
  int4* WBl        = (int4*)p;   p += (size_t)KC * 8 * DIM * 2 * 16;   // 512KB
  float* Zt        = (float*)p;  p += (size_t)KC * NPTS * 4;           // 4MB
  float* Gp        = (float*)p;  p += (size_t)KC * DIM * DIM * 4;      // 1MB

  const int prep_lds = 37312 * 4;  // 149,248 B dynamic LDS
  (void)hipFuncSetAttribute((const void*)prep_kernel,
      hipFuncAttributeMaxDynamicSharedMemorySize, prep_lds);

  xsplit_kernel<<<NPTS / 16, 256, 0, stream>>>(X, XBh, XBl);

  for (int s = 0; s < STAGES; ++s) {
    const float* cs = (s == 0) ? covs0 : covs_cur;
    const float* ms = (s == 0) ? means0 : means_cur;
    prep_kernel<<<KC, 256, prep_lds, stream>>>(cs, ms, WBh, WBl, mvec, kconst);
    estep_kernel<<<NPTS / 128, 256, 0, stream>>>(X, WBh, WBl, mvec, kconst,
                                                 Zout, Zt);
    if (s < STAGES - 1) {
      hipMemsetAsync(Gp, 0, (size_t)KC * DIM * DIM * 4, stream);
      gram_kernel<<<dim3(KC, NCHG), 256, 0, stream>>>(Zt, XBh, XBl, Gp, sp, twp);
    } else {
      moment_kernel<<<dim3(KC, NCHG), 128, 0, stream>>>(X, Zt, sp, twp);
    }
    reduce_means_kernel<<<8, 256, 0, stream>>>(sp, twp, means_cur, tw);
    if (s < STAGES - 1)
      finalize_cov_kernel<<<KC * DIM * DIM / 256, 256, 0, stream>>>(
          Gp, means_cur, tw, covs_cur);
  }
  out_kernel<<<(NPTS * DIM / 4) / 256, 256, 0, stream>>>(X, Zout, means_cur, out);
}